// Round 14
// baseline (113.857 us; speedup 1.0000x reference)
//
#include <hip/hip_runtime.h>
#include <hip/hip_bf16.h>
#include <math.h>

typedef __attribute__((ext_vector_type(16))) float f32x16;

#define MFMA8(A, B, C) __builtin_amdgcn_mfma_f32_32x32x16_fp8_fp8((long)(A), (long)(B), (C), 0, 0, 0)

__device__ __forceinline__ int pk4(float a, float b, float c, float d) {
    int w = __builtin_amdgcn_cvt_pk_fp8_f32(a, b, 0, false);   // bytes 0,1
    w = __builtin_amdgcn_cvt_pk_fp8_f32(c, d, w, true);        // bytes 2,3
    return w;
}

// ---------------- ws layout (bytes) ----------------
//   [0, 65536)        W1tp fp8: [kc 0..31][m 0..255][8] = fp8(W1[(kc*8+i)*256+m] * 16)
//   [65536, 98304)    W2tp fp8: [kc 0..31][m 0..127][8] = fp8(W2[(kc*8+i)*128+m] * 16)
//   [98304, 102400)   B3p  fp8: [kc 0..15][m 0..31][8], m<8: fp8(W3[k*8+m]*8); 8..15: fp8(AV[(m-8)*128+k]); else 0
//   [102400, 102432)  v2  : float[8] = sum_k AV[c][k]^2
//   [102432, 103456)  b1p : float[256]  (epilogue-order b1)
//   [103456, 103968)  b2p : float[128]  (epilogue-order b2)

__global__ void prep_all(const float* __restrict__ W1, const float* __restrict__ W2,
                         const float* __restrict__ W3, const float* __restrict__ AV,
                         const float* __restrict__ b1, const float* __restrict__ b2,
                         char* __restrict__ wp,
                         float* __restrict__ v2, float* __restrict__ b1p,
                         float* __restrict__ b2p) {
    if (blockIdx.x == 50) {                    // small-constant prep
        int t = threadIdx.x;
        {
            int mt = t >> 5, g = (t >> 4) & 1, r = t & 15;
            b1p[t] = b1[mt * 32 + 4 * g + (r & 3) + 8 * (r >> 2)];
        }
        if (t < 128) {
            int mt = t >> 5, g = (t >> 4) & 1, r = t & 15;
            b2p[t] = b2[mt * 32 + 4 * g + (r & 3) + 8 * (r >> 2)];
        }
        if (t < 64) {
            int c = t >> 3, jj = t & 7;
            float s = 0.f;
            for (int k = jj * 16; k < jj * 16 + 16; ++k) { float a = AV[c * 128 + k]; s = fmaf(a, a, s); }
            s += __shfl_xor(s, 1); s += __shfl_xor(s, 2); s += __shfl_xor(s, 4);
            if (jj == 0) v2[c] = s;
        }
        return;
    }
    int j = blockIdx.x * 256 + threadIdx.x;   // one 8-byte fragment per thread
    float f[8];
    if (j < 8192) {                            // W1tp
        int kc = j >> 8, m = j & 255;
        #pragma unroll
        for (int i = 0; i < 8; ++i) f[i] = W1[(kc * 8 + i) * 256 + m] * 16.f;
        int2 t; t.x = pk4(f[0], f[1], f[2], f[3]); t.y = pk4(f[4], f[5], f[6], f[7]);
        *(int2*)(wp + (size_t)j * 8) = t;
    } else if (j < 12288) {                    // W2tp
        int jj = j - 8192; int kc = jj >> 7, m = jj & 127;
        #pragma unroll
        for (int i = 0; i < 8; ++i) f[i] = W2[(kc * 8 + i) * 128 + m] * 16.f;
        int2 t; t.x = pk4(f[0], f[1], f[2], f[3]); t.y = pk4(f[4], f[5], f[6], f[7]);
        *(int2*)(wp + 65536 + (size_t)jj * 8) = t;
    } else if (j < 12800) {                    // B3p
        int jj = j - 12288; int kc = jj >> 5, m = jj & 31;
        #pragma unroll
        for (int i = 0; i < 8; ++i) {
            int k = kc * 8 + i;
            float v = 0.f;
            if (m < 8)       v = W3[k * 8 + m] * 8.f;
            else if (m < 16) v = AV[(m - 8) * 128 + k];
            f[i] = v;
        }
        int2 t; t.x = pk4(f[0], f[1], f[2], f[3]); t.y = pk4(f[4], f[5], f[6], f[7]);
        *(int2*)(wp + 98304 + (size_t)jj * 8) = t;
    }
}

// ---------------- main fused kernel (fp8, BM=64, 5 blocks/CU) ----------------
// 4096 blocks x 256 threads (4 waves), LDS 32KB -> 5 blocks/CU = 160KB exactly,
// 20 waves/CU (62.5%). GEMM1 split into 2 sequential m-tile passes so the live
// accumulator set is 32 regs not 64 -> fits the 102-reg cap at 5 waves/SIMD.
//   GEMM1': h^T  = W1tp @ x^T  M=256 N=64 K=256 (wave: pass mt in {2wv,2wv+1} x 2 n-tiles)
//   GEMM2': actT = W2tp @ h    M=128 N=64 K=256 (wave: m-tile wv x 2 n-tiles)
//   GEMM3': D3   = B3p @ act   M=32  N=64 K=128 (waves 0,1: one n-tile each)
// Weights pre-scaled x16 (W1,W2) / x8 (W3); unscaled via fmaf(acc,1/16,bias).
// LDS: x fp8 [64 rows][256B] @0 (act [64][128B] + a2[4][64]f32 @8192 reuse it);
//      h fp8 [64][256B] @16384.
// Swizzle: 8B chunk c of row r at slot c^(r&31) (x/h, 32 chunks) or c^(r&15) (act).
#define LDS_H 16384

__global__ __launch_bounds__(256, 5)
void openmax_mfma(const float* __restrict__ x,
                  const float* __restrict__ b3,
                  const float* __restrict__ walpha, const float* __restrict__ wbeta,
                  const float* __restrict__ wtau,
                  const char* __restrict__ wpack, const float* __restrict__ v2g,
                  const float* __restrict__ b1p, const float* __restrict__ b2p,
                  float* __restrict__ out) {
    __shared__ __align__(16) char smem[32768];
    const int tid = threadIdx.x;
    const int l = tid & 63, wv = tid >> 6;
    const int lo = l & 31, g = l >> 5;
    const long row0 = (long)blockIdx.x * 64;

    const unsigned long long* Ap1 = (const unsigned long long*)wpack;            // [kc*256+m]
    const unsigned long long* Ap2 = (const unsigned long long*)(wpack + 65536);  // [kc*128+m]
    const unsigned long long* Ap3 = (const unsigned long long*)(wpack + 98304);  // [kc*32+m]

    // ---- issue x loads first (HBM critical path): 16 float4/thread ----
    const float4* xg = (const float4*)(x + row0 * 256);
    float4 xv[16];
    #pragma unroll
    for (int i = 0; i < 16; ++i) xv[i] = xg[i * 256 + tid];

    // ---- convert + store x tile (64 rows x 256) as fp8, swizzled ----
    #pragma unroll
    for (int i = 0; i < 16; ++i) {
        int fc = i * 256 + tid;              // float4-chunk index (4096 total)
        int row = fc >> 6, c4 = fc & 63;
        int hc = c4 >> 1, half = c4 & 1;     // 8B fp8 chunk + half
        int w = pk4(xv[i].x, xv[i].y, xv[i].z, xv[i].w);
        *(int*)(smem + row * 256 + (((hc ^ (row & 31)) << 3) + half * 4)) = w;
    }
    __syncthreads();

    // ---- GEMM1': h^T = W1tp @ x^T, two sequential m-passes ----
    #pragma unroll
    for (int mt = 0; mt < 2; ++mt) {
        const int aRow = (wv * 2 + mt) * 32 + lo;
        unsigned long long pa[2], pb0[2], pb1[2];
        #pragma unroll
        for (int p = 0; p < 2; ++p) {
            int kc = p * 2 + g;
            pa[p]  = Ap1[kc * 256 + aRow];
            pb0[p] = *(const unsigned long long*)(smem + lo * 256 + ((kc ^ lo) << 3));
            pb1[p] = *(const unsigned long long*)(smem + (32 + lo) * 256 + ((kc ^ lo) << 3));
        }
        f32x16 a0, a1;
        #pragma unroll
        for (int i = 0; i < 16; ++i) { a0[i] = 0.f; a1[i] = 0.f; }
        #pragma unroll
        for (int ks = 0; ks < 16; ++ks) {
            const int slot = ks & 1;
            unsigned long long A = pa[slot], B0 = pb0[slot], B1 = pb1[slot];
            if (ks < 14) {
                int kc = (ks + 2) * 2 + g;
                pa[slot]  = Ap1[kc * 256 + aRow];
                pb0[slot] = *(const unsigned long long*)(smem + lo * 256 + ((kc ^ lo) << 3));
                pb1[slot] = *(const unsigned long long*)(smem + (32 + lo) * 256 + ((kc ^ lo) << 3));
            }
            a0 = MFMA8(A, B0, a0);
            a1 = MFMA8(A, B1, a1);
        }
        // unscale + bias + relu + pack fp8 to h LDS
        const float* bp = b1p + ((wv * 2 + mt) * 2 + g) * 16;
        float bia[16];
        *(float4*)(bia)      = *(const float4*)(bp);
        *(float4*)(bia + 4)  = *(const float4*)(bp + 4);
        *(float4*)(bia + 8)  = *(const float4*)(bp + 8);
        *(float4*)(bia + 12) = *(const float4*)(bp + 12);
        #pragma unroll
        for (int nt = 0; nt < 2; ++nt) {
            const f32x16& A = (nt == 0) ? a0 : a1;
            int b = nt * 32 + lo;
            int base = LDS_H + b * 256 + g * 4;
            #pragma unroll
            for (int q = 0; q < 4; ++q) {
                float v0 = fmaxf(fmaf(A[4 * q + 0], 0.0625f, bia[4 * q + 0]), 0.f);
                float v1 = fmaxf(fmaf(A[4 * q + 1], 0.0625f, bia[4 * q + 1]), 0.f);
                float v2_ = fmaxf(fmaf(A[4 * q + 2], 0.0625f, bia[4 * q + 2]), 0.f);
                float v3 = fmaxf(fmaf(A[4 * q + 3], 0.0625f, bia[4 * q + 3]), 0.f);
                int hc = (wv * 2 + mt) * 4 + q;
                *(int*)(smem + base + ((hc ^ (b & 31)) << 3)) = pk4(v0, v1, v2_, v3);
            }
        }
    }

    // ---- GEMM2 A prefetch BEFORE barrier ----
    const int aRow2 = wv * 32 + lo;
    unsigned long long pa2[2];
    #pragma unroll
    for (int p = 0; p < 2; ++p) {
        int kc = p * 2 + g;
        pa2[p] = Ap2[kc * 128 + aRow2];
    }
    __syncthreads();

    // ---- GEMM2': act^T = W2tp @ h ; act fp8 into dead x region + a2 ----
    {
        unsigned long long pb0[2], pb1[2];
        #pragma unroll
        for (int p = 0; p < 2; ++p) {
            int kc = p * 2 + g;
            pb0[p] = *(const unsigned long long*)(smem + LDS_H + lo * 256 + ((kc ^ lo) << 3));
            pb1[p] = *(const unsigned long long*)(smem + LDS_H + (32 + lo) * 256 + ((kc ^ lo) << 3));
        }
        f32x16 c0, c1;
        #pragma unroll
        for (int i = 0; i < 16; ++i) { c0[i] = 0.f; c1[i] = 0.f; }
        #pragma unroll
        for (int ks = 0; ks < 16; ++ks) {
            const int slot = ks & 1;
            unsigned long long A = pa2[slot], B0 = pb0[slot], B1 = pb1[slot];
            if (ks < 14) {
                int kc = (ks + 2) * 2 + g;
                pa2[slot] = Ap2[kc * 128 + aRow2];
                pb0[slot] = *(const unsigned long long*)(smem + LDS_H + lo * 256 + ((kc ^ lo) << 3));
                pb1[slot] = *(const unsigned long long*)(smem + LDS_H + (32 + lo) * 256 + ((kc ^ lo) << 3));
            }
            c0 = MFMA8(A, B0, c0);
            c1 = MFMA8(A, B1, c1);
        }
        const float* bp = b2p + (wv * 2 + g) * 16;
        float bia[16];
        *(float4*)(bia)      = *(const float4*)(bp);
        *(float4*)(bia + 4)  = *(const float4*)(bp + 4);
        *(float4*)(bia + 8)  = *(const float4*)(bp + 8);
        *(float4*)(bia + 12) = *(const float4*)(bp + 12);
        #pragma unroll
        for (int nt = 0; nt < 2; ++nt) {
            const f32x16& A = (nt == 0) ? c0 : c1;
            int b = nt * 32 + lo;
            int base = b * 128 + g * 4;
            float ss = 0.f;
            #pragma unroll
            for (int q = 0; q < 4; ++q) {
                float v0 = fmaxf(fmaf(A[4 * q + 0], 0.0625f, bia[4 * q + 0]), 0.f);
                float v1 = fmaxf(fmaf(A[4 * q + 1], 0.0625f, bia[4 * q + 1]), 0.f);
                float v2_ = fmaxf(fmaf(A[4 * q + 2], 0.0625f, bia[4 * q + 2]), 0.f);
                float v3 = fmaxf(fmaf(A[4 * q + 3], 0.0625f, bia[4 * q + 3]), 0.f);
                ss += v0 * v0 + v1 * v1 + v2_ * v2_ + v3 * v3;
                int ac = wv * 4 + q;
                *(int*)(smem + base + ((ac ^ (b & 15)) << 3)) = pk4(v0, v1, v2_, v3);
            }
            ss += __shfl_xor(ss, 32);
            if (g == 0) *(float*)(smem + 8192 + (wv * 64 + b) * 4) = ss;
        }
    }

    // ---- GEMM3 A preload + epilogue constants BEFORE barrier (waves 0,1) ----
    unsigned long long pa3[8];
    float4 e_b3[2], e_v2[2], e_al[2], e_be[2], e_ta[2];
    if (wv < 2) {
        #pragma unroll
        for (int p = 0; p < 8; ++p) {
            int kc = p * 2 + g;
            pa3[p] = Ap3[kc * 32 + lo];
        }
        e_b3[0] = *(const float4*)(b3);     e_b3[1] = *(const float4*)(b3 + 4);
        e_v2[0] = *(const float4*)(v2g);    e_v2[1] = *(const float4*)(v2g + 4);
        e_al[0] = *(const float4*)(walpha); e_al[1] = *(const float4*)(walpha + 4);
        e_be[0] = *(const float4*)(wbeta);  e_be[1] = *(const float4*)(wbeta + 4);
        e_ta[0] = *(const float4*)(wtau);   e_ta[1] = *(const float4*)(wtau + 4);
    }
    __syncthreads();

    // ---- GEMM3' + OpenMax epilogue (waves 0,1; wave wv owns rows wv*32..+32) ----
    if (wv < 2) {
        const int b = wv * 32 + lo;
        unsigned long long pb[8];
        #pragma unroll
        for (int p = 0; p < 8; ++p) {
            int kc = p * 2 + g;
            pb[p] = *(const unsigned long long*)(smem + b * 128 + ((kc ^ (b & 15)) << 3));
        }
        f32x16 acc;
        #pragma unroll
        for (int i = 0; i < 16; ++i) acc[i] = 0.f;
        #pragma unroll
        for (int ks = 0; ks < 8; ++ks)
            acc = MFMA8(pa3[ks], pb[ks], acc);

        // lane holds: logits(x8) classes 4g+j in acc[j], dots in acc[4+j]
        float oth[8];
        #pragma unroll
        for (int j = 0; j < 8; ++j) oth[j] = __shfl_xor(acc[j], 32);

        float a2v = 0.f;
        #pragma unroll
        for (int wq = 0; wq < 4; ++wq)
            a2v += *(const float*)(smem + 8192 + (wq * 64 + b) * 4);

        float m = 0.f, outv[8];
        #pragma unroll
        for (int c = 0; c < 8; ++c) {
            float lgv = ((c >> 2) == g) ? acc[c & 3]       : oth[c & 3];
            float dtv = ((c >> 2) == g) ? acc[4 + (c & 3)] : oth[4 + (c & 3)];
            float v2c = e_v2[c >> 2][c & 3];
            float d2 = a2v - 2.f * dtv + v2c;
            float dist = sqrtf(fmaxf(d2, 0.f));
            float sb = fmaxf(e_be[c >> 2][c & 3], 1e-6f);
            float sx = fmaxf(dist - e_ta[c >> 2][c & 3], 0.f);
            float t = sx / sb;
            float y = exp2f(e_al[c >> 2][c & 3] * log2f(t));   // t^alpha (t=0 -> 0)
            float cdf = 1.f - expf(-y);
            m = fmaxf(m, cdf);
            outv[c] = fmaf(lgv, 0.125f, e_b3[c >> 2][c & 3]);  // unscale W3 x8
        }
        float scale = (m > 0.5f) ? (1.f - m) : 1.f;
        if (g == 0) {
            float4 o0 = { outv[0] * scale, outv[1] * scale, outv[2] * scale, outv[3] * scale };
            float4 o1 = { outv[4] * scale, outv[5] * scale, outv[6] * scale, outv[7] * scale };
            float4* op = (float4*)(out + (row0 + b) * 8);
            op[0] = o0; op[1] = o1;
        }
    }
}

extern "C" void kernel_launch(void* const* d_in, const int* in_sizes, int n_in,
                              void* d_out, int out_size, void* d_ws, size_t ws_size,
                              hipStream_t stream) {
    const float* x      = (const float*)d_in[0];
    const float* W1     = (const float*)d_in[1];
    const float* b1     = (const float*)d_in[2];
    const float* W2     = (const float*)d_in[3];
    const float* b2     = (const float*)d_in[4];
    const float* W3     = (const float*)d_in[5];
    const float* b3     = (const float*)d_in[6];
    const float* walpha = (const float*)d_in[7];
    const float* wbeta  = (const float*)d_in[8];
    const float* wtau   = (const float*)d_in[9];
    const float* AV     = (const float*)d_in[10];
    float* out = (float*)d_out;

    char*  wpack = (char*)d_ws;
    float* v2    = (float*)((char*)d_ws + 102400);
    float* b1p   = (float*)((char*)d_ws + 102432);
    float* b2p   = (float*)((char*)d_ws + 103456);

    prep_all<<<51, 256, 0, stream>>>(W1, W2, W3, AV, b1, b2, wpack, v2, b1p, b2p);

    const int B = in_sizes[0] / 256;   // 262144 rows
    openmax_mfma<<<B / 64, 256, 0, stream>>>(x, b3, walpha, wbeta, wtau,
                                             wpack, v2, b1p, b2p, out);
}

// Round 15
// 75.498 us; speedup vs baseline: 1.5081x; 1.5081x over previous
//
#include <hip/hip_runtime.h>
#include <hip/hip_bf16.h>
#include <math.h>

typedef __attribute__((ext_vector_type(16))) float f32x16;

#define MFMA8(A, B, C) __builtin_amdgcn_mfma_f32_32x32x16_fp8_fp8((long)(A), (long)(B), (C), 0, 0, 0)

__device__ __forceinline__ int pk4(float a, float b, float c, float d) {
    int w = __builtin_amdgcn_cvt_pk_fp8_f32(a, b, 0, false);   // bytes 0,1
    w = __builtin_amdgcn_cvt_pk_fp8_f32(c, d, w, true);        // bytes 2,3
    return w;
}

// ---------------- ws layout (bytes) ----------------
//   [0, 65536)        W1tp fp8: [kc 0..31][m 0..255][8] = fp8(W1[(kc*8+i)*256+m] * 16)
//   [65536, 98304)    W2tp fp8: [kc 0..31][m 0..127][8] = fp8(W2[(kc*8+i)*128+m] * 16)
//   [98304, 102400)   B3p  fp8: [kc 0..15][m 0..31][8], m<8: fp8(W3[k*8+m]*8); 8..15: fp8(AV[(m-8)*128+k]); else 0
//   [102400, 102432)  v2  : float[8] = sum_k AV[c][k]^2
//   [102432, 103456)  b1p : float[256]  (epilogue-order b1)
//   [103456, 103968)  b2p : float[128]  (epilogue-order b2)

__global__ void prep_all(const float* __restrict__ W1, const float* __restrict__ W2,
                         const float* __restrict__ W3, const float* __restrict__ AV,
                         const float* __restrict__ b1, const float* __restrict__ b2,
                         char* __restrict__ wp,
                         float* __restrict__ v2, float* __restrict__ b1p,
                         float* __restrict__ b2p) {
    if (blockIdx.x == 50) {                    // small-constant prep
        int t = threadIdx.x;
        {
            int mt = t >> 5, g = (t >> 4) & 1, r = t & 15;
            b1p[t] = b1[mt * 32 + 4 * g + (r & 3) + 8 * (r >> 2)];
        }
        if (t < 128) {
            int mt = t >> 5, g = (t >> 4) & 1, r = t & 15;
            b2p[t] = b2[mt * 32 + 4 * g + (r & 3) + 8 * (r >> 2)];
        }
        if (t < 64) {
            int c = t >> 3, jj = t & 7;
            float s = 0.f;
            for (int k = jj * 16; k < jj * 16 + 16; ++k) { float a = AV[c * 128 + k]; s = fmaf(a, a, s); }
            s += __shfl_xor(s, 1); s += __shfl_xor(s, 2); s += __shfl_xor(s, 4);
            if (jj == 0) v2[c] = s;
        }
        return;
    }
    int j = blockIdx.x * 256 + threadIdx.x;   // one 8-byte fragment per thread
    float f[8];
    if (j < 8192) {                            // W1tp
        int kc = j >> 8, m = j & 255;
        #pragma unroll
        for (int i = 0; i < 8; ++i) f[i] = W1[(kc * 8 + i) * 256 + m] * 16.f;
        int2 t; t.x = pk4(f[0], f[1], f[2], f[3]); t.y = pk4(f[4], f[5], f[6], f[7]);
        *(int2*)(wp + (size_t)j * 8) = t;
    } else if (j < 12288) {                    // W2tp
        int jj = j - 8192; int kc = jj >> 7, m = jj & 127;
        #pragma unroll
        for (int i = 0; i < 8; ++i) f[i] = W2[(kc * 8 + i) * 128 + m] * 16.f;
        int2 t; t.x = pk4(f[0], f[1], f[2], f[3]); t.y = pk4(f[4], f[5], f[6], f[7]);
        *(int2*)(wp + 65536 + (size_t)jj * 8) = t;
    } else if (j < 12800) {                    // B3p
        int jj = j - 12288; int kc = jj >> 5, m = jj & 31;
        #pragma unroll
        for (int i = 0; i < 8; ++i) {
            int k = kc * 8 + i;
            float v = 0.f;
            if (m < 8)       v = W3[k * 8 + m] * 8.f;
            else if (m < 16) v = AV[(m - 8) * 128 + k];
            f[i] = v;
        }
        int2 t; t.x = pk4(f[0], f[1], f[2], f[3]); t.y = pk4(f[4], f[5], f[6], f[7]);
        *(int2*)(wp + 98304 + (size_t)jj * 8) = t;
    }
}

// ---------------- main fused kernel (fp8, BM=64) — R13 champion + hoisted prefetch ----------------
// 4096 blocks x 256 threads (4 waves), LDS 32KB, launch_bounds(256,4).
// (Do NOT use bound 5: R14 showed it pins VGPR=48 -> spills -> 2x slower.)
//   GEMM1': h^T  = W1tp @ x^T  M=256 N=64 K=256 (wave: m-tiles 2wv,2wv+1 x 2 n-tiles)
//   GEMM2': actT = W2tp @ h    M=128 N=64 K=256 (wave: m-tile wv x 2 n-tiles)
//   GEMM3': D3   = B3p @ act   M=32  N=64 K=128 (waves 0,1)
// Weights pre-scaled x16 (W1,W2) / x8 (W3); unscaled via fmaf(acc,1/16,bias).
// LDS: x fp8 [64 rows][256B] @0 (act [64][128B] + a2[4][64]f32 @8192 reuse it);
//      h fp8 [64][256B] @16384.
// Swizzle: 8B chunk c of row r at slot c^(r&31) (x/h) or c^(r&15) (act).
#define LDS_H 16384

__global__ __launch_bounds__(256, 4)
void openmax_mfma(const float* __restrict__ x,
                  const float* __restrict__ b3,
                  const float* __restrict__ walpha, const float* __restrict__ wbeta,
                  const float* __restrict__ wtau,
                  const char* __restrict__ wpack, const float* __restrict__ v2g,
                  const float* __restrict__ b1p, const float* __restrict__ b2p,
                  float* __restrict__ out) {
    __shared__ __align__(16) char smem[32768];
    const int tid = threadIdx.x;
    const int l = tid & 63, wv = tid >> 6;
    const int lo = l & 31, g = l >> 5;
    const long row0 = (long)blockIdx.x * 64;

    const unsigned long long* Ap1 = (const unsigned long long*)wpack;            // [kc*256+m]
    const unsigned long long* Ap2 = (const unsigned long long*)(wpack + 65536);  // [kc*128+m]
    const unsigned long long* Ap3 = (const unsigned long long*)(wpack + 98304);  // [kc*32+m]

    // ---- issue x loads first (HBM critical path): 16 float4/thread ----
    const float4* xg = (const float4*)(x + row0 * 256);
    float4 xv[16];
    #pragma unroll
    for (int i = 0; i < 16; ++i) xv[i] = xg[i * 256 + tid];

    // ---- GEMM1 A prefetch (L2) while x in flight (depth 2) ----
    const int aRow1 = wv * 64 + lo;          // m-tile 2wv; +32 for m-tile 2wv+1
    unsigned long long pa0[2], pa1[2];
    #pragma unroll
    for (int p = 0; p < 2; ++p) {
        int kc = p * 2 + g;
        pa0[p] = Ap1[kc * 256 + aRow1];
        pa1[p] = Ap1[kc * 256 + aRow1 + 32];
    }

    // ---- convert + store x tile (64 rows x 256) as fp8, swizzled ----
    #pragma unroll
    for (int i = 0; i < 16; ++i) {
        int fc = i * 256 + tid;              // float4-chunk index (4096 total)
        int row = fc >> 6, c4 = fc & 63;
        int hc = c4 >> 1, half = c4 & 1;     // 8B fp8 chunk + half
        int w = pk4(xv[i].x, xv[i].y, xv[i].z, xv[i].w);
        *(int*)(smem + row * 256 + (((hc ^ (row & 31)) << 3) + half * 4)) = w;
    }
    __syncthreads();

    const int aRow2 = wv * 32 + lo;
    unsigned long long pa2[2];

    // ---- GEMM1': h^T = W1tp @ x^T (16 ks, depth-2 pipeline) ----
    {
        unsigned long long pb0[2], pb1[2];
        #pragma unroll
        for (int p = 0; p < 2; ++p) {
            int kc = p * 2 + g;
            pb0[p] = *(const unsigned long long*)(smem + lo * 256 + ((kc ^ lo) << 3));
            pb1[p] = *(const unsigned long long*)(smem + (32 + lo) * 256 + ((kc ^ lo) << 3));
        }
        f32x16 a00, a01, a10, a11;
        #pragma unroll
        for (int i = 0; i < 16; ++i) { a00[i] = 0.f; a01[i] = 0.f; a10[i] = 0.f; a11[i] = 0.f; }
        #pragma unroll
        for (int ks = 0; ks < 16; ++ks) {
            const int slot = ks & 1;
            unsigned long long A0 = pa0[slot], A1 = pa1[slot], B0 = pb0[slot], B1 = pb1[slot];
            if (ks < 14) {
                int kc = (ks + 2) * 2 + g;
                pa0[slot] = Ap1[kc * 256 + aRow1];
                pa1[slot] = Ap1[kc * 256 + aRow1 + 32];
                pb0[slot] = *(const unsigned long long*)(smem + lo * 256 + ((kc ^ lo) << 3));
                pb1[slot] = *(const unsigned long long*)(smem + (32 + lo) * 256 + ((kc ^ lo) << 3));
            }
            a00 = MFMA8(A0, B0, a00);
            a01 = MFMA8(A0, B1, a01);
            a10 = MFMA8(A1, B0, a10);
            a11 = MFMA8(A1, B1, a11);
        }

        // ---- GEMM2 A prefetch issued HERE: overlaps the h epilogue below ----
        #pragma unroll
        for (int p = 0; p < 2; ++p) {
            int kc = p * 2 + g;
            pa2[p] = Ap2[kc * 128 + aRow2];
        }

        // unscale + bias + relu + pack fp8 to h LDS
        #pragma unroll
        for (int mt = 0; mt < 2; ++mt) {
            const float* bp = b1p + ((wv * 2 + mt) * 2 + g) * 16;
            float bia[16];
            *(float4*)(bia)      = *(const float4*)(bp);
            *(float4*)(bia + 4)  = *(const float4*)(bp + 4);
            *(float4*)(bia + 8)  = *(const float4*)(bp + 8);
            *(float4*)(bia + 12) = *(const float4*)(bp + 12);
            #pragma unroll
            for (int nt = 0; nt < 2; ++nt) {
                const f32x16& A = (mt == 0) ? (nt == 0 ? a00 : a01)
                                            : (nt == 0 ? a10 : a11);
                int b = nt * 32 + lo;
                int base = LDS_H + b * 256 + g * 4;
                #pragma unroll
                for (int q = 0; q < 4; ++q) {
                    float v0 = fmaxf(fmaf(A[4 * q + 0], 0.0625f, bia[4 * q + 0]), 0.f);
                    float v1 = fmaxf(fmaf(A[4 * q + 1], 0.0625f, bia[4 * q + 1]), 0.f);
                    float v2_ = fmaxf(fmaf(A[4 * q + 2], 0.0625f, bia[4 * q + 2]), 0.f);
                    float v3 = fmaxf(fmaf(A[4 * q + 3], 0.0625f, bia[4 * q + 3]), 0.f);
                    int hc = (wv * 2 + mt) * 4 + q;
                    *(int*)(smem + base + ((hc ^ (b & 31)) << 3)) = pk4(v0, v1, v2_, v3);
                }
            }
        }
    }
    __syncthreads();

    // ---- GEMM2': act^T = W2tp @ h ; act fp8 into dead x region + a2 ----
    {
        unsigned long long pb0[2], pb1[2];
        #pragma unroll
        for (int p = 0; p < 2; ++p) {
            int kc = p * 2 + g;
            pb0[p] = *(const unsigned long long*)(smem + LDS_H + lo * 256 + ((kc ^ lo) << 3));
            pb1[p] = *(const unsigned long long*)(smem + LDS_H + (32 + lo) * 256 + ((kc ^ lo) << 3));
        }
        f32x16 c0, c1;
        #pragma unroll
        for (int i = 0; i < 16; ++i) { c0[i] = 0.f; c1[i] = 0.f; }
        #pragma unroll
        for (int ks = 0; ks < 16; ++ks) {
            const int slot = ks & 1;
            unsigned long long A = pa2[slot], B0 = pb0[slot], B1 = pb1[slot];
            if (ks < 14) {
                int kc = (ks + 2) * 2 + g;
                pa2[slot] = Ap2[kc * 128 + aRow2];
                pb0[slot] = *(const unsigned long long*)(smem + LDS_H + lo * 256 + ((kc ^ lo) << 3));
                pb1[slot] = *(const unsigned long long*)(smem + LDS_H + (32 + lo) * 256 + ((kc ^ lo) << 3));
            }
            c0 = MFMA8(A, B0, c0);
            c1 = MFMA8(A, B1, c1);
        }
        const float* bp = b2p + (wv * 2 + g) * 16;
        float bia[16];
        *(float4*)(bia)      = *(const float4*)(bp);
        *(float4*)(bia + 4)  = *(const float4*)(bp + 4);
        *(float4*)(bia + 8)  = *(const float4*)(bp + 8);
        *(float4*)(bia + 12) = *(const float4*)(bp + 12);
        #pragma unroll
        for (int nt = 0; nt < 2; ++nt) {
            const f32x16& A = (nt == 0) ? c0 : c1;
            int b = nt * 32 + lo;
            int base = b * 128 + g * 4;
            float ss = 0.f;
            #pragma unroll
            for (int q = 0; q < 4; ++q) {
                float v0 = fmaxf(fmaf(A[4 * q + 0], 0.0625f, bia[4 * q + 0]), 0.f);
                float v1 = fmaxf(fmaf(A[4 * q + 1], 0.0625f, bia[4 * q + 1]), 0.f);
                float v2_ = fmaxf(fmaf(A[4 * q + 2], 0.0625f, bia[4 * q + 2]), 0.f);
                float v3 = fmaxf(fmaf(A[4 * q + 3], 0.0625f, bia[4 * q + 3]), 0.f);
                ss += v0 * v0 + v1 * v1 + v2_ * v2_ + v3 * v3;
                int ac = wv * 4 + q;
                *(int*)(smem + base + ((ac ^ (b & 15)) << 3)) = pk4(v0, v1, v2_, v3);
            }
            ss += __shfl_xor(ss, 32);
            if (g == 0) *(float*)(smem + 8192 + (wv * 64 + b) * 4) = ss;
        }
    }

    // ---- GEMM3 A preload + epilogue constants BEFORE barrier (waves 0,1) ----
    unsigned long long pa3[8];
    float4 e_b3[2], e_v2[2], e_al[2], e_be[2], e_ta[2];
    if (wv < 2) {
        #pragma unroll
        for (int p = 0; p < 8; ++p) {
            int kc = p * 2 + g;
            pa3[p] = Ap3[kc * 32 + lo];
        }
        e_b3[0] = *(const float4*)(b3);     e_b3[1] = *(const float4*)(b3 + 4);
        e_v2[0] = *(const float4*)(v2g);    e_v2[1] = *(const float4*)(v2g + 4);
        e_al[0] = *(const float4*)(walpha); e_al[1] = *(const float4*)(walpha + 4);
        e_be[0] = *(const float4*)(wbeta);  e_be[1] = *(const float4*)(wbeta + 4);
        e_ta[0] = *(const float4*)(wtau);   e_ta[1] = *(const float4*)(wtau + 4);
    }
    __syncthreads();

    // ---- GEMM3' + OpenMax epilogue (waves 0,1; wave wv owns rows wv*32..+32) ----
    if (wv < 2) {
        const int b = wv * 32 + lo;
        unsigned long long pb[8];
        #pragma unroll
        for (int p = 0; p < 8; ++p) {
            int kc = p * 2 + g;
            pb[p] = *(const unsigned long long*)(smem + b * 128 + ((kc ^ (b & 15)) << 3));
        }
        f32x16 acc;
        #pragma unroll
        for (int i = 0; i < 16; ++i) acc[i] = 0.f;
        #pragma unroll
        for (int ks = 0; ks < 8; ++ks)
            acc = MFMA8(pa3[ks], pb[ks], acc);

        // lane holds: logits(x8) classes 4g+j in acc[j], dots in acc[4+j]
        float oth[8];
        #pragma unroll
        for (int j = 0; j < 8; ++j) oth[j] = __shfl_xor(acc[j], 32);

        float a2v = 0.f;
        #pragma unroll
        for (int wq = 0; wq < 4; ++wq)
            a2v += *(const float*)(smem + 8192 + (wq * 64 + b) * 4);

        float m = 0.f, outv[8];
        #pragma unroll
        for (int c = 0; c < 8; ++c) {
            float lgv = ((c >> 2) == g) ? acc[c & 3]       : oth[c & 3];
            float dtv = ((c >> 2) == g) ? acc[4 + (c & 3)] : oth[4 + (c & 3)];
            float v2c = e_v2[c >> 2][c & 3];
            float d2 = a2v - 2.f * dtv + v2c;
            float dist = sqrtf(fmaxf(d2, 0.f));
            float sb = fmaxf(e_be[c >> 2][c & 3], 1e-6f);
            float sx = fmaxf(dist - e_ta[c >> 2][c & 3], 0.f);
            float t = sx / sb;
            float y = exp2f(e_al[c >> 2][c & 3] * log2f(t));   // t^alpha (t=0 -> 0)
            float cdf = 1.f - expf(-y);
            m = fmaxf(m, cdf);
            outv[c] = fmaf(lgv, 0.125f, e_b3[c >> 2][c & 3]);  // unscale W3 x8
        }
        float scale = (m > 0.5f) ? (1.f - m) : 1.f;
        if (g == 0) {
            float4 o0 = { outv[0] * scale, outv[1] * scale, outv[2] * scale, outv[3] * scale };
            float4 o1 = { outv[4] * scale, outv[5] * scale, outv[6] * scale, outv[7] * scale };
            float4* op = (float4*)(out + (row0 + b) * 8);
            op[0] = o0; op[1] = o1;
        }
    }
}

extern "C" void kernel_launch(void* const* d_in, const int* in_sizes, int n_in,
                              void* d_out, int out_size, void* d_ws, size_t ws_size,
                              hipStream_t stream) {
    const float* x      = (const float*)d_in[0];
    const float* W1     = (const float*)d_in[1];
    const float* b1     = (const float*)d_in[2];
    const float* W2     = (const float*)d_in[3];
    const float* b2     = (const float*)d_in[4];
    const float* W3     = (const float*)d_in[5];
    const float* b3     = (const float*)d_in[6];
    const float* walpha = (const float*)d_in[7];
    const float* wbeta  = (const float*)d_in[8];
    const float* wtau   = (const float*)d_in[9];
    const float* AV     = (const float*)d_in[10];
    float* out = (float*)d_out;

    char*  wpack = (char*)d_ws;
    float* v2    = (float*)((char*)d_ws + 102400);
    float* b1p   = (float*)((char*)d_ws + 102432);
    float* b2p   = (float*)((char*)d_ws + 103456);

    prep_all<<<51, 256, 0, stream>>>(W1, W2, W3, AV, b1, b2, wpack, v2, b1p, b2p);

    const int B = in_sizes[0] / 256;   // 262144 rows
    openmax_mfma<<<B / 64, 256, 0, stream>>>(x, b3, walpha, wbeta, wtau,
                                             wpack, v2, b1p, b2p, out);
}